// Round 7
// baseline (326.517 us; speedup 1.0000x reference)
//
#include <hip/hip_runtime.h>
#include <cstdint>
#include <cstddef>

// ---------------------------------------------------------------------------
// GenEdge R10:
//   cvt    : REWRITTEN: fully-coalesced float4 reads (2x 4KB dense segments
//            per block) -> padded LDS (132 f32/pixel, no 16-way conflicts) ->
//            per-pixel sumsq via 4 shfl_xor -> unit-norm f16 tiled layout with
//            the SAME perfectly-coalesced writes as before. Old version read
//            32B/lane at 512B stride; if cvt was the fixed ~114us gap sink,
//            this fixes it (floor ~21us at 124.5MB).
//   edge   : R9 structure unchanged; ONLY change: launch_bounds(256,3)->(256,4)
//            (cap 128 >= demand ~108, no spill expected - probe of the
//            occupancy cap; R9 measured 27% occ, 47% VALUBusy, 102us).
//   combine: sum halves, e=|gx|+|gy| (border zeroed), block-max -> atomicMax.
//   norm   : divide by global max.
// ---------------------------------------------------------------------------

typedef _Float16 half8 __attribute__((ext_vector_type(8)));
typedef float    f32x4 __attribute__((ext_vector_type(4)));

#define HW   400
#define NP   (HW*HW)
#define CCH  128
#define W16  416                 // padded width (26 groups of 16)
#define ROWE (W16*CCH)           // 53248 f16 elements per padded row
#define PAD  12
#define IEND 388                 // interior: [12, 388)
#define LDSF 132                 // padded f32 per pixel row (128+4)

// f16 cube layout per row: [pg(26)][ks(4)][q(4)][i(16)][j(8)] elements
// offset = pg*2048 + ks*512 + q*128 + i*8 + j
// => a wave's B-frag load for (group, ks) is base + lane*16 B: one coalesced
//    global_load_dwordx4 per (group, ks).

// ---------------- Phase 1: convert + normalize (coalesced R/W) -------------
__global__ void cvt_kernel(const float* __restrict__ cube,
                           _Float16* __restrict__ c16,
                           unsigned* __restrict__ gmax) {
  __shared__ float buf[16*LDSF];   // 8448 B
  __shared__ float part[16];
  int pg = blockIdx.x;          // 0..25 (pg 25 is all-pad)
  int r  = blockIdx.y;          // 0..399
  int t  = threadIdx.x;         // 0..255
  if (pg == 0 && r == 0 && t == 0) *gmax = 0u;   // every call (re-poisoned ws)
  if (pg == 25) {               // all 16 pixels are padding -> zero output
    half8 hz;
    #pragma unroll
    for (int j = 0; j < 8; ++j) hz[j] = (_Float16)0.f;
    *(half8*)(c16 + (size_t)r*ROWE + 25*2048 + t*8) = hz;
    return;
  }
  // coalesced read: 2048 consecutive floats; stream float s -> pixel s>>7,
  // channel s&127.  thread t loads s=4t and s=4t+1024.
  const float4* src4 = (const float4*)(cube + ((size_t)(r*HW + pg*16))*CCH);
  float4 fa = src4[t];
  float4 fb = src4[t + 256];
  int pa = t >> 5,        oa = (t & 31)*4;
  int pb = 8 + (t >> 5),  ob = (t & 31)*4;
  *(float4*)&buf[pa*LDSF + oa] = fa;
  *(float4*)&buf[pb*LDSF + ob] = fb;
  __syncthreads();
  // per-pixel sumsq: thread t -> pixel p = t>>4, chunk k = t&15 (8 ch each)
  int p = t >> 4, k = t & 15;
  const float4* pr = (const float4*)&buf[p*LDSF + k*8];
  float4 x0 = pr[0], x1 = pr[1];
  float ss = x0.x*x0.x + x0.y*x0.y + x0.z*x0.z + x0.w*x0.w
           + x1.x*x1.x + x1.y*x1.y + x1.z*x1.z + x1.w*x1.w;
  ss += __shfl_xor(ss, 1);
  ss += __shfl_xor(ss, 2);
  ss += __shfl_xor(ss, 4);
  ss += __shfl_xor(ss, 8);
  if (k == 0) part[p] = ss;
  __syncthreads();
  // write phase (same mapping as R9): t = ks*64+q*16+i; cb = t>>4 = ks*4+q
  int i = t & 15, cb = t >> 4;
  float tot = part[i];
  float sc = (tot > 0.f) ? rsqrtf(tot) : 0.f;
  const float4* vp = (const float4*)&buf[i*LDSF + cb*8];
  float4 v0 = vp[0], v1 = vp[1];
  half8 hv;
  hv[0] = (_Float16)(v0.x*sc); hv[1] = (_Float16)(v0.y*sc);
  hv[2] = (_Float16)(v0.z*sc); hv[3] = (_Float16)(v0.w*sc);
  hv[4] = (_Float16)(v1.x*sc); hv[5] = (_Float16)(v1.y*sc);
  hv[6] = (_Float16)(v1.z*sc); hv[7] = (_Float16)(v1.w*sc);
  *(half8*)(c16 + (size_t)r*ROWE + pg*2048 + t*8) = hv;
}

// ---------------- Phase 2: banded MFMA + SAD partials ----------------
__global__ __launch_bounds__(256, 4) void edge_kernel(
    const _Float16* __restrict__ c16,
    float* __restrict__ gxp, float* __restrict__ gyp) {
  // 2256 blocks = 8 XCDs x 282; per XCD contiguous row band.
  // Block: 4 waves, wave wv -> wb = wbq*4 + wv, all SAME row h and half.
  const int id  = blockIdx.x;
  const int g   = (id & 7)*282 + (id >> 3);
  const int row = g / 6;                 // 0..375
  const int rem = g - row*6;             // wbq*2 + half
  const int half = rem & 1;              // di half
  const int wbq  = rem >> 1;             // 0..2
  const int h   = row + PAD;             // 12..387
  const int wv  = threadIdx.x >> 6;      // wave 0..3
  const int wb  = wbq*4 + wv;            // 0..11
  const int l   = threadIdx.x & 63;
  const int c   = l & 15, q = l >> 4;
  const int w0  = PAD + 32*wb;
  const int g0  = 2*wb;                  // first B pixel-group

  // A-frags: center pixels of row h.  A[m=lane&15][k=q*8+j]
  half8 A[2][4];
  #pragma unroll
  for (int t = 0; t < 2; ++t) {
    int px = w0 + 16*t + c;              // <= 395 < 400
    const _Float16* p = c16 + (size_t)h*ROWE + (px >> 4)*2048 + q*128 + (px & 15)*8;
    #pragma unroll
    for (int ks = 0; ks < 4; ++ks)
      A[t][ks] = *(const half8*)(p + ks*512);
  }

  const float cq = (float)(c - 4*q);     // dj-12 = 16d - 12 - rr + (c-4q)

  // factored accumulators: S0 = sum w*sad, S1 = sum w*sad*ii
  float S0[2][3][4], S1[2][3][4];
  #pragma unroll
  for (int t = 0; t < 2; ++t)
    #pragma unroll
    for (int d = 0; d < 3; ++d)
      #pragma unroll
      for (int rr = 0; rr < 4; ++rr) { S0[t][d][rr] = 0.f; S1[t][d][rr] = 0.f; }

  const f32x4 z4 = {0.f, 0.f, 0.f, 0.f};
  const _Float16* bBase = c16 + g0*2048 + (size_t)l*8;
  // di=12 belongs to BOTH halves at weight 0.5.
  const int diLo = half ? 12 : 0;
  const int diHi = half ? 25 : 13;

  #pragma unroll 1
  for (int di = diLo; di < diHi; ++di) {
    const int r = h + di - PAD;          // 0..399
    const _Float16* rowB = bBase + (size_t)r*ROWE;

    f32x4 acc[2][3];

    #pragma unroll
    for (int ks = 0; ks < 4; ++ks) {
      half8 B0 = *(const half8*)(rowB + 0*2048 + ks*512);
      half8 B1 = *(const half8*)(rowB + 1*2048 + ks*512);
      half8 B2 = *(const half8*)(rowB + 2*2048 + ks*512);
      half8 B3 = *(const half8*)(rowB + 3*2048 + ks*512);
      if (ks == 0) {
        acc[0][0] = __builtin_amdgcn_mfma_f32_16x16x32_f16(A[0][0], B0, z4, 0,0,0);
        acc[0][1] = __builtin_amdgcn_mfma_f32_16x16x32_f16(A[0][0], B1, z4, 0,0,0);
        acc[0][2] = __builtin_amdgcn_mfma_f32_16x16x32_f16(A[0][0], B2, z4, 0,0,0);
        acc[1][0] = __builtin_amdgcn_mfma_f32_16x16x32_f16(A[1][0], B1, z4, 0,0,0);
        acc[1][1] = __builtin_amdgcn_mfma_f32_16x16x32_f16(A[1][0], B2, z4, 0,0,0);
        acc[1][2] = __builtin_amdgcn_mfma_f32_16x16x32_f16(A[1][0], B3, z4, 0,0,0);
      } else {
        acc[0][0] = __builtin_amdgcn_mfma_f32_16x16x32_f16(A[0][ks], B0, acc[0][0], 0,0,0);
        acc[0][1] = __builtin_amdgcn_mfma_f32_16x16x32_f16(A[0][ks], B1, acc[0][1], 0,0,0);
        acc[0][2] = __builtin_amdgcn_mfma_f32_16x16x32_f16(A[0][ks], B2, acc[0][2], 0,0,0);
        acc[1][0] = __builtin_amdgcn_mfma_f32_16x16x32_f16(A[1][ks], B1, acc[1][0], 0,0,0);
        acc[1][1] = __builtin_amdgcn_mfma_f32_16x16x32_f16(A[1][ks], B2, acc[1][1], 0,0,0);
        acc[1][2] = __builtin_amdgcn_mfma_f32_16x16x32_f16(A[1][ks], B3, acc[1][2], 0,0,0);
      }
    }

    // per-di scalars only; all per-element weighting deferred to epilogue.
    // ratio >= 0 guaranteed (nonneg unit vectors) -> no sign reflection.
    const float ii  = (float)((di <= 12) ? di : 24 - di);
    const float w0s = (di == 12) ? 0.5f : 1.0f;
    const float w1s = w0s * ii;

    #pragma unroll
    for (int t = 0; t < 2; ++t)
      #pragma unroll
      for (int d = 0; d < 3; ++d)
        #pragma unroll
        for (int rr = 0; rr < 4; ++rr) {
          float x  = acc[t][d][rr];                    // cos in [0, 1+eps)
          float sq = __builtin_amdgcn_sqrtf(fmaxf(1.0f - x, 0.0f));
          float pl = fmaf(x, -0.0187292994f, 0.0742610134f);
          pl = fmaf(pl, x, -0.2121143967f);
          pl = fmaf(pl, x,  1.5707287572f);
          float sad = sq * pl;                         // acos(x), |err|<7e-5
          S0[t][d][rr] = fmaf(sad, w0s, S0[t][d][rr]);
          S1[t][d][rr] = fmaf(sad, w1s, S1[t][d][rr]);
        }
  }

  // epilogue: apply di-invariant weights once.
  //   kx = p + sg*ii            -> gx = p*S0 + sg*S1
  //   ky = s_h*(12 + mnj - ii)  -> gy = s_h*((12+mnj)*S0 - S1)
  const float s_h = half ? 1.0f : -1.0f;
  float gx[2][4], gy[2][4];
  #pragma unroll
  for (int t = 0; t < 2; ++t)
    #pragma unroll
    for (int rr = 0; rr < 4; ++rr) { gx[t][rr] = 0.f; gy[t][rr] = 0.f; }

  #pragma unroll
  for (int d = 0; d < 3; ++d)
    #pragma unroll
    for (int rr = 0; rr < 4; ++rr) {
      float p   = cq + (float)(16*d - 12 - rr);   // dj - 12 (integer)
      float ap  = fabsf(p);
      float mnj = 12.0f - ap;                     // >=0 iff |dj-12|<=12
      bool  ok  = mnj >= 0.0f;
      float sg  = fminf(fmaxf(p, -1.0f), 1.0f);   // sgn(p)
      float wy  = 12.0f + mnj;
      #pragma unroll
      for (int t = 0; t < 2; ++t) {
        float s0 = S0[t][d][rr], s1 = S1[t][d][rr];
        float gxc = ok ? fmaf(sg, s1, p*s0) : 0.0f;
        float gyc = ok ? s_h*fmaf(wy, s0, -s1) : 0.0f;
        gx[t][rr] += gxc;
        gy[t][rr] += gyc;
      }
    }

  // reduce over c (lane bits 0..3); writer lanes c == rr store partials
  const int hoff = half*NP + h*HW;
  #pragma unroll
  for (int t = 0; t < 2; ++t)
    #pragma unroll
    for (int rr = 0; rr < 4; ++rr) {
      float sgx = gx[t][rr], sgy = gy[t][rr];
      #pragma unroll
      for (int m = 1; m < 16; m <<= 1) {
        sgx += __shfl_xor(sgx, m);
        sgy += __shfl_xor(sgy, m);
      }
      if (c == rr) {
        int w = w0 + 16*t + 4*q + rr;    // <= 395, disjoint across waves
        gxp[hoff + w] = sgx;
        gyp[hoff + w] = sgy;
      }
    }
}

// ---------------- Phase 3a: combine halves + global max ----------------
__global__ void combine_kernel(float* __restrict__ gxp,
                               const float* __restrict__ gyp,
                               unsigned* __restrict__ gmax) {
  __shared__ float wm[4];
  int idx = blockIdx.x*256 + threadIdx.x;      // 625*256 = NP exactly
  int hh = idx / HW;
  int ww = idx - hh*HW;
  float e = 0.f;
  if (hh >= PAD && hh < IEND && ww >= PAD && ww < IEND)
    e = fabsf(gxp[idx] + gxp[NP + idx]) + fabsf(gyp[idx] + gyp[NP + idx]);
  gxp[idx] = e;                                // edge buffer aliases gxp[0]
  float m = e;
  #pragma unroll
  for (int off = 1; off < 64; off <<= 1) m = fmaxf(m, __shfl_xor(m, off));
  if ((threadIdx.x & 63) == 0) wm[threadIdx.x >> 6] = m;
  __syncthreads();
  if (threadIdx.x == 0) {
    float mm = fmaxf(fmaxf(wm[0], wm[1]), fmaxf(wm[2], wm[3]));
    atomicMax(gmax, __float_as_uint(mm));      // e >= 0: uint order ok
  }
}

// ---------------- Phase 3b: normalize ----------------
__global__ void norm_kernel(const float* __restrict__ edge,
                            const unsigned* __restrict__ gmax,
                            float* __restrict__ out) {
  int idx = blockIdx.x*256 + threadIdx.x;
  float mv = __uint_as_float(*gmax);
  out[idx] = edge[idx] / mv;                   // border already 0
}

// ---------------- launch ----------------
extern "C" void kernel_launch(void* const* d_in, const int* in_sizes, int n_in,
                              void* d_out, int out_size, void* d_ws, size_t ws_size,
                              hipStream_t stream) {
  const float* cube = (const float*)d_in[0];   // (1,400,400,128) f32
  char* ws = (char*)d_ws;
  _Float16* c16  = (_Float16*)(ws);                     // 42,598,400 B
  float*    gxp  = (float*)(ws + 42598400);             // 2*NP floats
  float*    gyp  = (float*)(ws + 42598400 + 8*NP);      // 2*NP floats
  unsigned* gmax = (unsigned*)(ws + 42598400 + 16*NP);  // 4 B  (~45.2 MB total)

  cvt_kernel<<<dim3(26, 400), 256, 0, stream>>>(cube, c16, gmax);
  edge_kernel<<<2256, 256, 0, stream>>>(c16, gxp, gyp);
  combine_kernel<<<NP/256, 256, 0, stream>>>(gxp, gyp, gmax);
  norm_kernel<<<NP/256, 256, 0, stream>>>(gxp, gmax, (float*)d_out);
}

// Round 10
// 232.750 us; speedup vs baseline: 1.4029x; 1.4029x over previous
//
#include <hip/hip_runtime.h>
#include <cstdint>
#include <cstddef>

// ---------------------------------------------------------------------------
// GenEdge R11 (resubmit x2 — R7/R8 benches never ran):
//   cvt    : coalesced float4 -> padded LDS -> f16 tiled (R10 structure) but
//            FAT blocks: grid (26,40), each block does 10 row-tiles in a
//            grid-stride loop (1040 blocks vs 10400; probes dispatch overhead
//            vs harness-floor for the fixed ~110us gap).
//   edge   : 16-COL waves (was 32): A 16 regs, S0/S1 24, acc 12, B 12 ->
//            ~80 total (was ~135). Same total MFMA/SAD work, 2x waves, +50%
//            B-load instrs (L1-hot). Block = 4 waves = adjacent wb, same row
//            and di-half; 6 distinct B groups per block. Grid 4512 =
//            376 rows x 2 halves x 6 wbq, XCD-chunked. __launch_bounds__(256)
//            ONLY - no min-waves cap (96/128-reg caps both caused the
//            compiler to mis-split the unified file and spill; R10 WRITE_SIZE
//            40MB). Occupancy should land ~5 waves/SIMD naturally.
//            Factored weighting + sign-free SAD + zero-C init (proven R9).
//   combine: sum halves, e=|gx|+|gy| (border zeroed), block-max -> atomicMax.
//   norm   : divide by global max.
// ---------------------------------------------------------------------------

typedef _Float16 half8 __attribute__((ext_vector_type(8)));
typedef float    f32x4 __attribute__((ext_vector_type(4)));

#define HW   400
#define NP   (HW*HW)
#define CCH  128
#define W16  416                 // padded width (26 groups of 16)
#define ROWE (W16*CCH)           // 53248 f16 elements per padded row
#define PAD  12
#define IEND 388                 // interior: [12, 388)
#define LDSF 132                 // padded f32 per pixel row (128+4)

// f16 cube layout per row: [pg(26)][ks(4)][q(4)][i(16)][j(8)] elements
// offset = pg*2048 + ks*512 + q*128 + i*8 + j

// ---------------- Phase 1: convert + normalize (coalesced, fat blocks) -----
__global__ void cvt_kernel(const float* __restrict__ cube,
                           _Float16* __restrict__ c16,
                           unsigned* __restrict__ gmax) {
  __shared__ float buf[16*LDSF];   // 8448 B
  __shared__ float part[16];
  int pg = blockIdx.x;          // 0..25 (pg 25 is all-pad)
  int rb = blockIdx.y;          // 0..39 -> rows rb*10 .. rb*10+9
  int t  = threadIdx.x;         // 0..255
  if (pg == 0 && rb == 0 && t == 0) *gmax = 0u;  // every call (re-poisoned ws)
  int pa = t >> 5, oa = (t & 31)*4;
  int p  = t >> 4, k  = t & 15;
  int i  = t & 15, cb = t >> 4;
  for (int r = rb*10; r < rb*10 + 10; ++r) {
    if (pg == 25) {             // all 16 pixels are padding -> zero output
      half8 hz;
      #pragma unroll
      for (int j = 0; j < 8; ++j) hz[j] = (_Float16)0.f;
      *(half8*)(c16 + (size_t)r*ROWE + 25*2048 + t*8) = hz;
      continue;                 // block-uniform branch: barrier-safe
    }
    // coalesced read: 2048 consecutive floats (16 pixels x 128 ch)
    const float4* src4 = (const float4*)(cube + ((size_t)(r*HW + pg*16))*CCH);
    float4 fa = src4[t];
    float4 fb = src4[t + 256];
    __syncthreads();            // WAR: previous iteration's readers done
    *(float4*)&buf[pa*LDSF + oa]     = fa;
    *(float4*)&buf[(8+pa)*LDSF + oa] = fb;
    __syncthreads();
    const float4* pr = (const float4*)&buf[p*LDSF + k*8];
    float4 x0 = pr[0], x1 = pr[1];
    float ss = x0.x*x0.x + x0.y*x0.y + x0.z*x0.z + x0.w*x0.w
             + x1.x*x1.x + x1.y*x1.y + x1.z*x1.z + x1.w*x1.w;
    ss += __shfl_xor(ss, 1);
    ss += __shfl_xor(ss, 2);
    ss += __shfl_xor(ss, 4);
    ss += __shfl_xor(ss, 8);
    if (k == 0) part[p] = ss;
    __syncthreads();
    float tot = part[i];
    float sc = (tot > 0.f) ? rsqrtf(tot) : 0.f;
    const float4* vp = (const float4*)&buf[i*LDSF + cb*8];
    float4 v0 = vp[0], v1 = vp[1];
    half8 hv;
    hv[0] = (_Float16)(v0.x*sc); hv[1] = (_Float16)(v0.y*sc);
    hv[2] = (_Float16)(v0.z*sc); hv[3] = (_Float16)(v0.w*sc);
    hv[4] = (_Float16)(v1.x*sc); hv[5] = (_Float16)(v1.y*sc);
    hv[6] = (_Float16)(v1.z*sc); hv[7] = (_Float16)(v1.w*sc);
    *(half8*)(c16 + (size_t)r*ROWE + pg*2048 + t*8) = hv;
  }
}

// ---------------- Phase 2: banded MFMA + SAD partials ----------------
__global__ __launch_bounds__(256) void edge_kernel(
    const _Float16* __restrict__ c16,
    float* __restrict__ gxp, float* __restrict__ gyp) {
  // 4512 blocks = 8 XCDs x 564; per XCD contiguous row band.
  // Block: 4 waves, wave wv -> wb = wbq*4 + wv (16-col tile), SAME row+half.
  const int id  = blockIdx.x;
  const int g   = (id & 7)*564 + (id >> 3);
  const int row = g / 12;                // 0..375
  const int rem = g - row*12;            // wbq*2 + half
  const int half = rem & 1;              // di half
  const int wbq  = rem >> 1;             // 0..5
  const int h   = row + PAD;             // 12..387
  const int wv  = threadIdx.x >> 6;      // wave 0..3
  const int wb  = wbq*4 + wv;            // 0..23
  const int l   = threadIdx.x & 63;
  const int c   = l & 15, q = l >> 4;
  const int w0  = PAD + 16*wb;           // first center col of tile
  // B groups needed: wb, wb+1, wb+2 (cols [16wb, 16wb+48) padded = dj window)

  // A-frags: center pixels w0..w0+15 of row h.  A[m=lane&15][k=q*8+j]
  half8 A[4];
  {
    int px = w0 + c;                     // <= 395 < 400
    const _Float16* pA = c16 + (size_t)h*ROWE + (px >> 4)*2048 + q*128 + (px & 15)*8;
    #pragma unroll
    for (int ks = 0; ks < 4; ++ks)
      A[ks] = *(const half8*)(pA + ks*512);
  }

  const float cq = (float)(c - 4*q);     // dj-12 = 16d - 12 - rr + (c-4q)

  // factored accumulators: S0 = sum w*sad, S1 = sum w*sad*ii
  float S0[3][4], S1[3][4];
  #pragma unroll
  for (int d = 0; d < 3; ++d)
    #pragma unroll
    for (int rr = 0; rr < 4; ++rr) { S0[d][rr] = 0.f; S1[d][rr] = 0.f; }

  const f32x4 z4 = {0.f, 0.f, 0.f, 0.f};
  const _Float16* bBase = c16 + wb*2048 + (size_t)l*8;
  // di=12 belongs to BOTH halves at weight 0.5.
  const int diLo = half ? 12 : 0;
  const int diHi = half ? 25 : 13;

  #pragma unroll 1
  for (int di = diLo; di < diHi; ++di) {
    const int r = h + di - PAD;          // 0..399
    const _Float16* rowB = bBase + (size_t)r*ROWE;

    f32x4 acc[3];

    #pragma unroll
    for (int ks = 0; ks < 4; ++ks) {
      half8 B0 = *(const half8*)(rowB + 0*2048 + ks*512);
      half8 B1 = *(const half8*)(rowB + 1*2048 + ks*512);
      half8 B2 = *(const half8*)(rowB + 2*2048 + ks*512);
      if (ks == 0) {
        acc[0] = __builtin_amdgcn_mfma_f32_16x16x32_f16(A[0], B0, z4, 0,0,0);
        acc[1] = __builtin_amdgcn_mfma_f32_16x16x32_f16(A[0], B1, z4, 0,0,0);
        acc[2] = __builtin_amdgcn_mfma_f32_16x16x32_f16(A[0], B2, z4, 0,0,0);
      } else {
        acc[0] = __builtin_amdgcn_mfma_f32_16x16x32_f16(A[ks], B0, acc[0], 0,0,0);
        acc[1] = __builtin_amdgcn_mfma_f32_16x16x32_f16(A[ks], B1, acc[1], 0,0,0);
        acc[2] = __builtin_amdgcn_mfma_f32_16x16x32_f16(A[ks], B2, acc[2], 0,0,0);
      }
    }

    // per-di scalars only; per-element weighting deferred to epilogue.
    // ratio >= 0 guaranteed (nonneg unit vectors) -> no sign reflection.
    const float ii  = (float)((di <= 12) ? di : 24 - di);
    const float w0s = (di == 12) ? 0.5f : 1.0f;
    const float w1s = w0s * ii;

    #pragma unroll
    for (int d = 0; d < 3; ++d)
      #pragma unroll
      for (int rr = 0; rr < 4; ++rr) {
        float x  = acc[d][rr];                       // cos in [0, 1+eps)
        float sq = __builtin_amdgcn_sqrtf(fmaxf(1.0f - x, 0.0f));
        float pl = fmaf(x, -0.0187292994f, 0.0742610134f);
        pl = fmaf(pl, x, -0.2121143967f);
        pl = fmaf(pl, x,  1.5707287572f);
        float sad = sq * pl;                         // acos(x), |err|<7e-5
        S0[d][rr] = fmaf(sad, w0s, S0[d][rr]);
        S1[d][rr] = fmaf(sad, w1s, S1[d][rr]);
      }
  }

  // epilogue: apply di-invariant weights once.
  //   kx = p + sg*ii            -> gx = p*S0 + sg*S1
  //   ky = s_h*(12 + mnj - ii)  -> gy = s_h*((12+mnj)*S0 - S1)
  const float s_h = half ? 1.0f : -1.0f;
  float gx[4], gy[4];
  #pragma unroll
  for (int rr = 0; rr < 4; ++rr) { gx[rr] = 0.f; gy[rr] = 0.f; }

  #pragma unroll
  for (int d = 0; d < 3; ++d)
    #pragma unroll
    for (int rr = 0; rr < 4; ++rr) {
      float p   = cq + (float)(16*d - 12 - rr);   // dj - 12 (integer)
      float ap  = fabsf(p);
      float mnj = 12.0f - ap;                     // >=0 iff |dj-12|<=12
      bool  ok  = mnj >= 0.0f;
      float sg  = fminf(fmaxf(p, -1.0f), 1.0f);   // sgn(p)
      float wy  = 12.0f + mnj;
      float s0 = S0[d][rr], s1 = S1[d][rr];
      gx[rr] += ok ? fmaf(sg, s1, p*s0) : 0.0f;
      gy[rr] += ok ? s_h*fmaf(wy, s0, -s1) : 0.0f;
    }

  // reduce over c (lane bits 0..3); writer lanes c == rr store partials
  const int hoff = half*NP + h*HW;
  #pragma unroll
  for (int rr = 0; rr < 4; ++rr) {
    float sgx = gx[rr], sgy = gy[rr];
    #pragma unroll
    for (int m = 1; m < 16; m <<= 1) {
      sgx += __shfl_xor(sgx, m);
      sgy += __shfl_xor(sgy, m);
    }
    if (c == rr) {
      int w = w0 + 4*q + rr;             // <= 395, disjoint across waves
      gxp[hoff + w] = sgx;
      gyp[hoff + w] = sgy;
    }
  }
}

// ---------------- Phase 3a: combine halves + global max ----------------
__global__ void combine_kernel(float* __restrict__ gxp,
                               const float* __restrict__ gyp,
                               unsigned* __restrict__ gmax) {
  __shared__ float wm[4];
  int idx = blockIdx.x*256 + threadIdx.x;      // 625*256 = NP exactly
  int hh = idx / HW;
  int ww = idx - hh*HW;
  float e = 0.f;
  if (hh >= PAD && hh < IEND && ww >= PAD && ww < IEND)
    e = fabsf(gxp[idx] + gxp[NP + idx]) + fabsf(gyp[idx] + gyp[NP + idx]);
  gxp[idx] = e;                                // edge buffer aliases gxp[0]
  float m = e;
  #pragma unroll
  for (int off = 1; off < 64; off <<= 1) m = fmaxf(m, __shfl_xor(m, off));
  if ((threadIdx.x & 63) == 0) wm[threadIdx.x >> 6] = m;
  __syncthreads();
  if (threadIdx.x == 0) {
    float mm = fmaxf(fmaxf(wm[0], wm[1]), fmaxf(wm[2], wm[3]));
    atomicMax(gmax, __float_as_uint(mm));      // e >= 0: uint order ok
  }
}

// ---------------- Phase 3b: normalize ----------------
__global__ void norm_kernel(const float* __restrict__ edge,
                            const unsigned* __restrict__ gmax,
                            float* __restrict__ out) {
  int idx = blockIdx.x*256 + threadIdx.x;
  float mv = __uint_as_float(*gmax);
  out[idx] = edge[idx] / mv;                   // border already 0
}

// ---------------- launch ----------------
extern "C" void kernel_launch(void* const* d_in, const int* in_sizes, int n_in,
                              void* d_out, int out_size, void* d_ws, size_t ws_size,
                              hipStream_t stream) {
  const float* cube = (const float*)d_in[0];   // (1,400,400,128) f32
  char* ws = (char*)d_ws;
  _Float16* c16  = (_Float16*)(ws);                     // 42,598,400 B
  float*    gxp  = (float*)(ws + 42598400);             // 2*NP floats
  float*    gyp  = (float*)(ws + 42598400 + 8*NP);      // 2*NP floats
  unsigned* gmax = (unsigned*)(ws + 42598400 + 16*NP);  // 4 B  (~45.2 MB total)

  cvt_kernel<<<dim3(26, 40), 256, 0, stream>>>(cube, c16, gmax);
  edge_kernel<<<4512, 256, 0, stream>>>(c16, gxp, gyp);
  combine_kernel<<<NP/256, 256, 0, stream>>>(gxp, gyp, gmax);
  norm_kernel<<<NP/256, 256, 0, stream>>>(gxp, gmax, (float*)d_out);
}

// Round 11
// 216.148 us; speedup vs baseline: 1.5106x; 1.0768x over previous
//
#include <hip/hip_runtime.h>
#include <cstdint>
#include <cstddef>

// ---------------------------------------------------------------------------
// GenEdge R12:
//   cvt    : R11 fat-block coalesced version (unchanged).
//   edge   : R9 structure (32-col waves, 4-wave WG same row+half, adjacent wb,
//            half-split di, plain stores) + SOFTWARE PIPELINE: all 16 B-loads
//            for di+1 issue right after di's MFMA phase, BEFORE the ~356-cyc
//            SAD chain -> covers ~200-cyc L2 latency (R9/R11 measured
//            VALUBusy ~50%: in-order issue put next-di loads after SAD,
//            stalling MFMA every iter). B regs (64) live through SAD:
//            demand ~190; launch_bounds(256,2) = 256-reg ceiling (ABOVE
//            demand - a guard, not a squeeze; 96/128 squeezes spilled).
//            Factored weighting + sign-free SAD + zero-C init (proven).
//   combine: sum halves, e=|gx|+|gy| (border zeroed), block-max -> atomicMax.
//   norm   : divide by global max.
// ---------------------------------------------------------------------------

typedef _Float16 half8 __attribute__((ext_vector_type(8)));
typedef float    f32x4 __attribute__((ext_vector_type(4)));

#define HW   400
#define NP   (HW*HW)
#define CCH  128
#define W16  416                 // padded width (26 groups of 16)
#define ROWE (W16*CCH)           // 53248 f16 elements per padded row
#define PAD  12
#define IEND 388                 // interior: [12, 388)
#define LDSF 132                 // padded f32 per pixel row (128+4)

// f16 cube layout per row: [pg(26)][ks(4)][q(4)][i(16)][j(8)] elements
// offset = pg*2048 + ks*512 + q*128 + i*8 + j

// ---------------- Phase 1: convert + normalize (coalesced, fat blocks) -----
__global__ void cvt_kernel(const float* __restrict__ cube,
                           _Float16* __restrict__ c16,
                           unsigned* __restrict__ gmax) {
  __shared__ float buf[16*LDSF];   // 8448 B
  __shared__ float part[16];
  int pg = blockIdx.x;          // 0..25 (pg 25 is all-pad)
  int rb = blockIdx.y;          // 0..39 -> rows rb*10 .. rb*10+9
  int t  = threadIdx.x;         // 0..255
  if (pg == 0 && rb == 0 && t == 0) *gmax = 0u;  // every call (re-poisoned ws)
  int pa = t >> 5, oa = (t & 31)*4;
  int p  = t >> 4, k  = t & 15;
  int i  = t & 15, cb = t >> 4;
  for (int r = rb*10; r < rb*10 + 10; ++r) {
    if (pg == 25) {             // all 16 pixels are padding -> zero output
      half8 hz;
      #pragma unroll
      for (int j = 0; j < 8; ++j) hz[j] = (_Float16)0.f;
      *(half8*)(c16 + (size_t)r*ROWE + 25*2048 + t*8) = hz;
      continue;                 // block-uniform branch: barrier-safe
    }
    // coalesced read: 2048 consecutive floats (16 pixels x 128 ch)
    const float4* src4 = (const float4*)(cube + ((size_t)(r*HW + pg*16))*CCH);
    float4 fa = src4[t];
    float4 fb = src4[t + 256];
    __syncthreads();            // WAR: previous iteration's readers done
    *(float4*)&buf[pa*LDSF + oa]     = fa;
    *(float4*)&buf[(8+pa)*LDSF + oa] = fb;
    __syncthreads();
    const float4* pr = (const float4*)&buf[p*LDSF + k*8];
    float4 x0 = pr[0], x1 = pr[1];
    float ss = x0.x*x0.x + x0.y*x0.y + x0.z*x0.z + x0.w*x0.w
             + x1.x*x1.x + x1.y*x1.y + x1.z*x1.z + x1.w*x1.w;
    ss += __shfl_xor(ss, 1);
    ss += __shfl_xor(ss, 2);
    ss += __shfl_xor(ss, 4);
    ss += __shfl_xor(ss, 8);
    if (k == 0) part[p] = ss;
    __syncthreads();
    float tot = part[i];
    float sc = (tot > 0.f) ? rsqrtf(tot) : 0.f;
    const float4* vp = (const float4*)&buf[i*LDSF + cb*8];
    float4 v0 = vp[0], v1 = vp[1];
    half8 hv;
    hv[0] = (_Float16)(v0.x*sc); hv[1] = (_Float16)(v0.y*sc);
    hv[2] = (_Float16)(v0.z*sc); hv[3] = (_Float16)(v0.w*sc);
    hv[4] = (_Float16)(v1.x*sc); hv[5] = (_Float16)(v1.y*sc);
    hv[6] = (_Float16)(v1.z*sc); hv[7] = (_Float16)(v1.w*sc);
    *(half8*)(c16 + (size_t)r*ROWE + pg*2048 + t*8) = hv;
  }
}

// ---------------- Phase 2: banded MFMA + SAD partials (pipelined) ----------
__global__ __launch_bounds__(256, 2) void edge_kernel(
    const _Float16* __restrict__ c16,
    float* __restrict__ gxp, float* __restrict__ gyp) {
  // 2256 blocks = 8 XCDs x 282; per XCD contiguous row band.
  // Block: 4 waves, wave wv -> wb = wbq*4 + wv, all SAME row h and half.
  const int id  = blockIdx.x;
  const int g   = (id & 7)*282 + (id >> 3);
  const int row = g / 6;                 // 0..375
  const int rem = g - row*6;             // wbq*2 + half
  const int half = rem & 1;              // di half
  const int wbq  = rem >> 1;             // 0..2
  const int h   = row + PAD;             // 12..387
  const int wv  = threadIdx.x >> 6;      // wave 0..3
  const int wb  = wbq*4 + wv;            // 0..11
  const int l   = threadIdx.x & 63;
  const int c   = l & 15, q = l >> 4;
  const int w0  = PAD + 32*wb;
  const int g0  = 2*wb;                  // first B pixel-group

  // A-frags: center pixels of row h.  A[m=lane&15][k=q*8+j]
  half8 A[2][4];
  #pragma unroll
  for (int t = 0; t < 2; ++t) {
    int px = w0 + 16*t + c;              // <= 395 < 400
    const _Float16* p = c16 + (size_t)h*ROWE + (px >> 4)*2048 + q*128 + (px & 15)*8;
    #pragma unroll
    for (int ks = 0; ks < 4; ++ks)
      A[t][ks] = *(const half8*)(p + ks*512);
  }

  const float cq = (float)(c - 4*q);     // dj-12 = 16d - 12 - rr + (c-4q)

  // factored accumulators: S0 = sum w*sad, S1 = sum w*sad*ii
  float S0[2][3][4], S1[2][3][4];
  #pragma unroll
  for (int t = 0; t < 2; ++t)
    #pragma unroll
    for (int d = 0; d < 3; ++d)
      #pragma unroll
      for (int rr = 0; rr < 4; ++rr) { S0[t][d][rr] = 0.f; S1[t][d][rr] = 0.f; }

  const f32x4 z4 = {0.f, 0.f, 0.f, 0.f};
  const _Float16* bBase = c16 + g0*2048 + (size_t)l*8;
  // di=12 belongs to BOTH halves at weight 0.5.
  const int diLo = half ? 12 : 0;
  const int diHi = half ? 25 : 13;

  // B frags for the CURRENT di, preloaded; refilled for di+1 after the MFMA
  // phase and before the SAD chain (software pipeline).
  half8 B[4][4];                         // [group][ks], 64 VGPRs
  {
    const _Float16* rowB = bBase + (size_t)(h + diLo - PAD)*ROWE;
    #pragma unroll
    for (int gg = 0; gg < 4; ++gg)
      #pragma unroll
      for (int ks = 0; ks < 4; ++ks)
        B[gg][ks] = *(const half8*)(rowB + gg*2048 + ks*512);
  }

  #pragma unroll 1
  for (int di = diLo; di < diHi; ++di) {
    // ---- MFMA phase (consumes B) ----
    f32x4 acc[2][3];
    #pragma unroll
    for (int ks = 0; ks < 4; ++ks) {
      if (ks == 0) {
        acc[0][0] = __builtin_amdgcn_mfma_f32_16x16x32_f16(A[0][0], B[0][0], z4, 0,0,0);
        acc[0][1] = __builtin_amdgcn_mfma_f32_16x16x32_f16(A[0][0], B[1][0], z4, 0,0,0);
        acc[0][2] = __builtin_amdgcn_mfma_f32_16x16x32_f16(A[0][0], B[2][0], z4, 0,0,0);
        acc[1][0] = __builtin_amdgcn_mfma_f32_16x16x32_f16(A[1][0], B[1][0], z4, 0,0,0);
        acc[1][1] = __builtin_amdgcn_mfma_f32_16x16x32_f16(A[1][0], B[2][0], z4, 0,0,0);
        acc[1][2] = __builtin_amdgcn_mfma_f32_16x16x32_f16(A[1][0], B[3][0], z4, 0,0,0);
      } else {
        acc[0][0] = __builtin_amdgcn_mfma_f32_16x16x32_f16(A[0][ks], B[0][ks], acc[0][0], 0,0,0);
        acc[0][1] = __builtin_amdgcn_mfma_f32_16x16x32_f16(A[0][ks], B[1][ks], acc[0][1], 0,0,0);
        acc[0][2] = __builtin_amdgcn_mfma_f32_16x16x32_f16(A[0][ks], B[2][ks], acc[0][2], 0,0,0);
        acc[1][0] = __builtin_amdgcn_mfma_f32_16x16x32_f16(A[1][ks], B[1][ks], acc[1][0], 0,0,0);
        acc[1][1] = __builtin_amdgcn_mfma_f32_16x16x32_f16(A[1][ks], B[2][ks], acc[1][1], 0,0,0);
        acc[1][2] = __builtin_amdgcn_mfma_f32_16x16x32_f16(A[1][ks], B[3][ks], acc[1][2], 0,0,0);
      }
    }

    // ---- prefetch B for di+1 (issued before the SAD chain; its ~356-cyc
    //      VALU tail covers the ~200-cyc L2 latency) ----
    if (di + 1 < diHi) {
      const _Float16* rowB = bBase + (size_t)(h + di + 1 - PAD)*ROWE;
      #pragma unroll
      for (int gg = 0; gg < 4; ++gg)
        #pragma unroll
        for (int ks = 0; ks < 4; ++ks)
          B[gg][ks] = *(const half8*)(rowB + gg*2048 + ks*512);
    }

    // ---- SAD phase (consumes acc; per-di scalars only) ----
    const float ii  = (float)((di <= 12) ? di : 24 - di);
    const float w0s = (di == 12) ? 0.5f : 1.0f;
    const float w1s = w0s * ii;

    #pragma unroll
    for (int t = 0; t < 2; ++t)
      #pragma unroll
      for (int d = 0; d < 3; ++d)
        #pragma unroll
        for (int rr = 0; rr < 4; ++rr) {
          float x  = acc[t][d][rr];                    // cos in [0, 1+eps)
          float sq = __builtin_amdgcn_sqrtf(fmaxf(1.0f - x, 0.0f));
          float pl = fmaf(x, -0.0187292994f, 0.0742610134f);
          pl = fmaf(pl, x, -0.2121143967f);
          pl = fmaf(pl, x,  1.5707287572f);
          float sad = sq * pl;                         // acos(x), |err|<7e-5
          S0[t][d][rr] = fmaf(sad, w0s, S0[t][d][rr]);
          S1[t][d][rr] = fmaf(sad, w1s, S1[t][d][rr]);
        }
  }

  // epilogue: apply di-invariant weights once.
  //   kx = p + sg*ii            -> gx = p*S0 + sg*S1
  //   ky = s_h*(12 + mnj - ii)  -> gy = s_h*((12+mnj)*S0 - S1)
  const float s_h = half ? 1.0f : -1.0f;
  float gx[2][4], gy[2][4];
  #pragma unroll
  for (int t = 0; t < 2; ++t)
    #pragma unroll
    for (int rr = 0; rr < 4; ++rr) { gx[t][rr] = 0.f; gy[t][rr] = 0.f; }

  #pragma unroll
  for (int d = 0; d < 3; ++d)
    #pragma unroll
    for (int rr = 0; rr < 4; ++rr) {
      float p   = cq + (float)(16*d - 12 - rr);   // dj - 12 (integer)
      float ap  = fabsf(p);
      float mnj = 12.0f - ap;                     // >=0 iff |dj-12|<=12
      bool  ok  = mnj >= 0.0f;
      float sg  = fminf(fmaxf(p, -1.0f), 1.0f);   // sgn(p)
      float wy  = 12.0f + mnj;
      #pragma unroll
      for (int t = 0; t < 2; ++t) {
        float s0 = S0[t][d][rr], s1 = S1[t][d][rr];
        float gxc = ok ? fmaf(sg, s1, p*s0) : 0.0f;
        float gyc = ok ? s_h*fmaf(wy, s0, -s1) : 0.0f;
        gx[t][rr] += gxc;
        gy[t][rr] += gyc;
      }
    }

  // reduce over c (lane bits 0..3); writer lanes c == rr store partials
  const int hoff = half*NP + h*HW;
  #pragma unroll
  for (int t = 0; t < 2; ++t)
    #pragma unroll
    for (int rr = 0; rr < 4; ++rr) {
      float sgx = gx[t][rr], sgy = gy[t][rr];
      #pragma unroll
      for (int m = 1; m < 16; m <<= 1) {
        sgx += __shfl_xor(sgx, m);
        sgy += __shfl_xor(sgy, m);
      }
      if (c == rr) {
        int w = w0 + 16*t + 4*q + rr;    // <= 395, disjoint across waves
        gxp[hoff + w] = sgx;
        gyp[hoff + w] = sgy;
      }
    }
}

// ---------------- Phase 3a: combine halves + global max ----------------
__global__ void combine_kernel(float* __restrict__ gxp,
                               const float* __restrict__ gyp,
                               unsigned* __restrict__ gmax) {
  __shared__ float wm[4];
  int idx = blockIdx.x*256 + threadIdx.x;      // 625*256 = NP exactly
  int hh = idx / HW;
  int ww = idx - hh*HW;
  float e = 0.f;
  if (hh >= PAD && hh < IEND && ww >= PAD && ww < IEND)
    e = fabsf(gxp[idx] + gxp[NP + idx]) + fabsf(gyp[idx] + gyp[NP + idx]);
  gxp[idx] = e;                                // edge buffer aliases gxp[0]
  float m = e;
  #pragma unroll
  for (int off = 1; off < 64; off <<= 1) m = fmaxf(m, __shfl_xor(m, off));
  if ((threadIdx.x & 63) == 0) wm[threadIdx.x >> 6] = m;
  __syncthreads();
  if (threadIdx.x == 0) {
    float mm = fmaxf(fmaxf(wm[0], wm[1]), fmaxf(wm[2], wm[3]));
    atomicMax(gmax, __float_as_uint(mm));      // e >= 0: uint order ok
  }
}

// ---------------- Phase 3b: normalize ----------------
__global__ void norm_kernel(const float* __restrict__ edge,
                            const unsigned* __restrict__ gmax,
                            float* __restrict__ out) {
  int idx = blockIdx.x*256 + threadIdx.x;
  float mv = __uint_as_float(*gmax);
  out[idx] = edge[idx] / mv;                   // border already 0
}

// ---------------- launch ----------------
extern "C" void kernel_launch(void* const* d_in, const int* in_sizes, int n_in,
                              void* d_out, int out_size, void* d_ws, size_t ws_size,
                              hipStream_t stream) {
  const float* cube = (const float*)d_in[0];   // (1,400,400,128) f32
  char* ws = (char*)d_ws;
  _Float16* c16  = (_Float16*)(ws);                     // 42,598,400 B
  float*    gxp  = (float*)(ws + 42598400);             // 2*NP floats
  float*    gyp  = (float*)(ws + 42598400 + 8*NP);      // 2*NP floats
  unsigned* gmax = (unsigned*)(ws + 42598400 + 16*NP);  // 4 B  (~45.2 MB total)

  cvt_kernel<<<dim3(26, 40), 256, 0, stream>>>(cube, c16, gmax);
  edge_kernel<<<2256, 256, 0, stream>>>(c16, gxp, gyp);
  combine_kernel<<<NP/256, 256, 0, stream>>>(gxp, gyp, gmax);
  norm_kernel<<<NP/256, 256, 0, stream>>>(gxp, gmax, (float*)d_out);
}